// Round 12
// baseline (361.447 us; speedup 1.0000x reference)
//
#include <hip/hip_runtime.h>
#include <math.h>

#define NN   100000
#define EE   1600000
#define FIN  256
#define NCLS 16
#define NEG  0.2f

#define NEDGE (EE + NN)     // with self-loops
#define WBKT  256           // dsts per bucket
#define NBKT  ((NN + WBKT - 1) / WBKT)   // 391
#define CAP   5120          // per-bucket capacity (mean 4352)
#define ABLK  4096          // edges per binA block
#define NABLK ((NEDGE + ABLK - 1) / ABLK)  // 416
#define NGBLK ((NN + 63) / 64)             // 1563 gemm1 blocks
#define NG1   576                          // gemm1 blocks fused with binA (~29us, ~binA dur)
#define NG2   (NGBLK - NG1)                // 987 fused with binC

// ---- workspace layout (4-byte element offsets) ----
#define OFF_GCNT  0                          // [392] zeroed each call
#define OFF_BASE  392                        // [392]
#define OFF_ROW   784                        // [NN+1]
#define OFF_BKT   100788                     // [NBKT*CAP] packed (src<<8)|dlow
#define OFF_ADJ   (OFF_BKT + NBKT*CAP)       // [NEDGE]
#define OFF_H1B   (OFF_ADJ + NEDGE)          // [NN*64] bf16 (pre-attn values)
#define OFF_H1E   (OFF_H1B + NN*32)          // [NN*64] bf16 (post-ELU)
#define OFF_AL1S  (OFF_H1E + NN*32)          // [NN*8]
#define OFF_AL1D  (OFF_AL1S + NN*8)          // [NN*8]
#define OFF_H2B   (OFF_AL1D + NN*8)          // [NN*16] bf16
#define OFF_AL2S  (OFF_H2B + NN*8)           // [NN]
#define OFF_AL2D  (OFF_AL2S + NN)            // [NN]

__device__ __forceinline__ float lrelu(float x) { return x >= 0.f ? x : NEG * x; }
__device__ __forceinline__ unsigned short f2bf(float x) {
    unsigned u = __float_as_uint(x);
    return (unsigned short)((u + 0x7FFF + ((u >> 16) & 1)) >> 16);   // RNE
}
__device__ __forceinline__ float bf2f(unsigned short b) {
    return __uint_as_float(((unsigned)b) << 16);
}
__device__ __forceinline__ float bflo(unsigned u) { return __uint_as_float(u << 16); }
__device__ __forceinline__ float bfhi(unsigned u) { return __uint_as_float(u & 0xFFFF0000u); }

// ================= role bodies (shared LDS carved from smem) =================

// ---- gemm1 body: 64x64 tile, 4x4 register tile, reg-prefetch dbuf ----
// smem usage: sxT 8704 B + sW 8192 B = 16896 B
__device__ __forceinline__ void gemm1_body(
    char* smem, int n0, int t,
    const float* __restrict__ x, const float* __restrict__ W1,
    const float* __restrict__ a1s, const float* __restrict__ a1d,
    unsigned short* __restrict__ h1b, float* __restrict__ al1s, float* __restrict__ al1d)
{
    float (*sxT)[68] = (float(*)[68])smem;
    float (*sW)[64]  = (float(*)[64])(smem + 32 * 68 * 4);
    const int tr = t >> 4, tc = t & 15;

    const int xr0 = t >> 3,         xf0 = t & 7;
    const int xr1 = (t + 256) >> 3, xf1 = (t + 256) & 7;
    const int wr0 = t >> 4,         wf0 = t & 15;
    const int wr1 = (t + 256) >> 4, wf1 = (t + 256) & 15;
    const int nx0 = n0 + xr0, nx1 = n0 + xr1;

    float acc[4][4] = {};
    float4 px0, px1, pw0, pw1;

    px0 = (nx0 < NN) ? *(const float4*)(x + (size_t)nx0 * FIN + xf0 * 4)
                     : make_float4(0.f, 0.f, 0.f, 0.f);
    px1 = (nx1 < NN) ? *(const float4*)(x + (size_t)nx1 * FIN + xf1 * 4)
                     : make_float4(0.f, 0.f, 0.f, 0.f);
    pw0 = *(const float4*)(W1 + (size_t)wr0 * 64 + wf0 * 4);
    pw1 = *(const float4*)(W1 + (size_t)wr1 * 64 + wf1 * 4);

    for (int kc = 0; kc < 256; kc += 32) {
        __syncthreads();
        sxT[xf0 * 4 + 0][xr0] = px0.x;
        sxT[xf0 * 4 + 1][xr0] = px0.y;
        sxT[xf0 * 4 + 2][xr0] = px0.z;
        sxT[xf0 * 4 + 3][xr0] = px0.w;
        sxT[xf1 * 4 + 0][xr1] = px1.x;
        sxT[xf1 * 4 + 1][xr1] = px1.y;
        sxT[xf1 * 4 + 2][xr1] = px1.z;
        sxT[xf1 * 4 + 3][xr1] = px1.w;
        *(float4*)&sW[wr0][wf0 * 4] = pw0;
        *(float4*)&sW[wr1][wf1 * 4] = pw1;
        __syncthreads();

        if (kc + 32 < 256) {
            int kn = kc + 32;
            px0 = (nx0 < NN) ? *(const float4*)(x + (size_t)nx0 * FIN + kn + xf0 * 4)
                             : make_float4(0.f, 0.f, 0.f, 0.f);
            px1 = (nx1 < NN) ? *(const float4*)(x + (size_t)nx1 * FIN + kn + xf1 * 4)
                             : make_float4(0.f, 0.f, 0.f, 0.f);
            pw0 = *(const float4*)(W1 + (size_t)(kn + wr0) * 64 + wf0 * 4);
            pw1 = *(const float4*)(W1 + (size_t)(kn + wr1) * 64 + wf1 * 4);
        }

        #pragma unroll
        for (int k = 0; k < 32; ++k) {
            float4 a = *(const float4*)&sxT[k][tr * 4];
            float4 b = *(const float4*)&sW[k][tc * 4];
            acc[0][0] += a.x * b.x; acc[0][1] += a.x * b.y; acc[0][2] += a.x * b.z; acc[0][3] += a.x * b.w;
            acc[1][0] += a.y * b.x; acc[1][1] += a.y * b.y; acc[1][2] += a.y * b.z; acc[1][3] += a.y * b.w;
            acc[2][0] += a.z * b.x; acc[2][1] += a.z * b.y; acc[2][2] += a.z * b.z; acc[2][3] += a.z * b.w;
            acc[3][0] += a.w * b.x; acc[3][1] += a.w * b.y; acc[3][2] += a.w * b.z; acc[3][3] += a.w * b.w;
        }
    }

    #pragma unroll
    for (int j = 0; j < 4; ++j) {
        int n = n0 + tr * 4 + j;
        if (n < NN) {
            ushort4 v = make_ushort4(f2bf(acc[j][0]), f2bf(acc[j][1]), f2bf(acc[j][2]), f2bf(acc[j][3]));
            *(ushort4*)(h1b + (size_t)n * 64 + tc * 4) = v;
        }
    }

    float sa[4], da[4];
    #pragma unroll
    for (int u = 0; u < 4; ++u) { sa[u] = a1s[tc * 4 + u]; da[u] = a1d[tc * 4 + u]; }
    #pragma unroll
    for (int j = 0; j < 4; ++j) {
        float vs = acc[j][0] * sa[0] + acc[j][1] * sa[1] + acc[j][2] * sa[2] + acc[j][3] * sa[3];
        float vd = acc[j][0] * da[0] + acc[j][1] * da[1] + acc[j][2] * da[2] + acc[j][3] * da[3];
        vs += __shfl_xor(vs, 1, 64);
        vd += __shfl_xor(vd, 1, 64);
        int n = n0 + tr * 4 + j;
        if (!(tc & 1) && n < NN) {
            al1s[n * 8 + (tc >> 1)] = vs;
            al1d[n * 8 + (tc >> 1)] = vd;
        }
    }
}

// ---- binA body: bin edges by dst>>8.  smem: 2*NBKT*4 = 3128 B ----
__device__ __forceinline__ void binA_body(
    char* smem, int blk, int t,
    const int* __restrict__ esrc, const int* __restrict__ edst,
    int* __restrict__ gcnt, unsigned* __restrict__ bkt)
{
    int* lcnt  = (int*)smem;
    int* lbase = lcnt + NBKT;
    const int e0 = blk * ABLK;
    for (int i = t; i < NBKT; i += 256) lcnt[i] = 0;
    __syncthreads();

    unsigned wrd[16];
    unsigned short bb[16], ll[16];
    #pragma unroll
    for (int j = 0; j < 16; ++j) {
        int ei = e0 + j * 256 + t;
        bb[j] = 0xFFFFu;
        if (ei < NEDGE) {
            int s, d;
            if (ei < EE) { s = esrc[ei]; d = edst[ei]; } else { s = d = ei - EE; }
            int b = d >> 8;
            wrd[j] = ((unsigned)s << 8) | (unsigned)(d & 255);
            bb[j] = (unsigned short)b;
            ll[j] = (unsigned short)atomicAdd(&lcnt[b], 1);
        }
    }
    __syncthreads();
    for (int i = t; i < NBKT; i += 256)
        lbase[i] = lcnt[i] ? atomicAdd(&gcnt[i], lcnt[i]) : 0;
    __syncthreads();
    #pragma unroll
    for (int j = 0; j < 16; ++j) {
        if (bb[j] != 0xFFFFu) {
            int b = bb[j];
            bkt[(size_t)b * CAP + lbase[b] + ll[j]] = wrd[j];
        }
    }
}

// ---- binC body: per-bucket local sort.  smem: 20480 + 3072 = 23552 B ----
__device__ __forceinline__ void binC_body(
    char* smem, int g, int t,
    const int* __restrict__ gcnt, const int* __restrict__ base,
    const unsigned* __restrict__ bkt, int* __restrict__ row, int* __restrict__ adj)
{
    unsigned* wd = (unsigned*)smem;            // CAP u32 = 20480 B
    int* hist = (int*)(smem + CAP * 4);
    int* pref = hist + 256;
    int* cnt2 = pref + 256;
    const int cn = gcnt[g], bs = base[g];
    hist[t] = 0; cnt2[t] = 0;
    __syncthreads();
    for (int i = t; i < cn; i += 256) {
        unsigned w = bkt[(size_t)g * CAP + i];
        wd[i] = w;
        atomicAdd(&hist[w & 255], 1);
    }
    __syncthreads();
    int v = hist[t];
    pref[t] = v;
    __syncthreads();
    for (int off = 1; off < 256; off <<= 1) {
        int u = (t >= off) ? pref[t - off] : 0;
        __syncthreads();
        pref[t] += u;
        __syncthreads();
    }
    int ex = pref[t] - v;                 // exclusive local prefix
    int n = g * 256 + t;
    if (n < NN) row[n] = bs + ex;
    pref[t] = ex;
    __syncthreads();
    for (int i = t; i < cn; i += 256) {
        unsigned w = wd[i];
        int dl = w & 255;
        int p = atomicAdd(&cnt2[dl], 1);
        adj[bs + pref[dl] + p] = (int)(w >> 8);
    }
}

// ================= fused launches =================

// fused1: binA (blocks 0..NABLK-1)  ||  gemm1 tiles [0, NG1)
__global__ __launch_bounds__(256) void k_binA_gemm1(
    const int* __restrict__ esrc, const int* __restrict__ edst,
    int* __restrict__ gcnt, unsigned* __restrict__ bkt,
    const float* __restrict__ x, const float* __restrict__ W1,
    const float* __restrict__ a1s, const float* __restrict__ a1d,
    unsigned short* __restrict__ h1b, float* __restrict__ al1s, float* __restrict__ al1d)
{
    __shared__ __align__(16) char smem[16896];   // union of roles (max, not sum)
    const int t = threadIdx.x;
    if (blockIdx.x < NABLK)
        binA_body(smem, blockIdx.x, t, esrc, edst, gcnt, bkt);
    else
        gemm1_body(smem, (blockIdx.x - NABLK) * 64, t, x, W1, a1s, a1d, h1b, al1s, al1d);
}

// fused2: binC (blocks 0..NBKT-1)  ||  gemm1 tiles [NG1, NGBLK)
__global__ __launch_bounds__(256) void k_binC_gemm1(
    const int* __restrict__ gcnt, const int* __restrict__ base,
    const unsigned* __restrict__ bkt, int* __restrict__ row, int* __restrict__ adj,
    const float* __restrict__ x, const float* __restrict__ W1,
    const float* __restrict__ a1s, const float* __restrict__ a1d,
    unsigned short* __restrict__ h1b, float* __restrict__ al1s, float* __restrict__ al1d)
{
    __shared__ __align__(16) char smem[23552];   // union of roles (max, not sum)
    const int t = threadIdx.x;
    if (blockIdx.x < NBKT)
        binC_body(smem, blockIdx.x, t, gcnt, base, bkt, row, adj);
    else
        gemm1_body(smem, (NG1 + (int)blockIdx.x - NBKT) * 64, t, x, W1, a1s, a1d, h1b, al1s, al1d);
}

// ---------- CSR build, phase B: scan bucket counts -> bases ----------
__global__ __launch_bounds__(512) void k_scanB(
    const int* __restrict__ gcnt, int* __restrict__ base, int* __restrict__ row)
{
    __shared__ int s[512];
    int t = threadIdx.x;
    int v = (t < NBKT) ? gcnt[t] : 0;
    s[t] = v;
    __syncthreads();
    for (int off = 1; off < 512; off <<= 1) {
        int u = (t >= off) ? s[t - off] : 0;
        __syncthreads();
        s[t] += u;
        __syncthreads();
    }
    if (t <= NBKT) base[t] = s[t] - v;   // exclusive; base[NBKT] = NEDGE
    if (t == 0) row[NN] = NEDGE;
}

// ---------- layer 1 aggregation: 4 edges x 16 lanes, uint2 value loads ----------
__global__ __launch_bounds__(256) void k_agg1(
    const int* __restrict__ row, const int* __restrict__ adj,
    const float* __restrict__ al1s, const float* __restrict__ al1d,
    const unsigned* __restrict__ h1b2, const float* __restrict__ b1,
    unsigned* __restrict__ h1e2)
{
    const int wv = threadIdx.x >> 6, lane = threadIdx.x & 63;
    const int n = blockIdx.x * 4 + wv;
    const int q = lane >> 4;           // edge slot in 4-pack
    const int r = lane & 15;           // channel quad -> channels 4r..4r+3
    const int h = r >> 1;              // head
    const float ald = al1d[n * 8 + h];
    const int r0 = row[n], r1 = row[n + 1];

    float dsum = 0.f, ax = 0.f, ay = 0.f, bx = 0.f, by = 0.f;
    for (int c0 = r0; c0 < r1; c0 += 64) {
        int li = c0 + lane;
        int adjv = adj[li < r1 ? li : r0];      // chunk preload, coalesced
        int m = r1 - c0; if (m > 64) m = 64;
        int k = 0;
        for (; k + 16 <= m; k += 16) {
            int s0 = __shfl(adjv, k + 0  + q, 64);
            int s1 = __shfl(adjv, k + 4  + q, 64);
            int s2 = __shfl(adjv, k + 8  + q, 64);
            int s3 = __shfl(adjv, k + 12 + q, 64);
            float a0 = al1s[s0 * 8 + h];
            float a1 = al1s[s1 * 8 + h];
            float a2 = al1s[s2 * 8 + h];
            float a3 = al1s[s3 * 8 + h];
            uint2 u0 = *(const uint2*)(h1b2 + s0 * 32 + r * 2);
            uint2 u1 = *(const uint2*)(h1b2 + s1 * 32 + r * 2);
            uint2 u2 = *(const uint2*)(h1b2 + s2 * 32 + r * 2);
            uint2 u3 = *(const uint2*)(h1b2 + s3 * 32 + r * 2);
            float w0 = __expf(lrelu(a0 + ald));
            float w1 = __expf(lrelu(a1 + ald));
            float w2 = __expf(lrelu(a2 + ald));
            float w3 = __expf(lrelu(a3 + ald));
            dsum += (w0 + w1) + (w2 + w3);
            ax += w0 * bflo(u0.x) + w1 * bflo(u1.x) + w2 * bflo(u2.x) + w3 * bflo(u3.x);
            ay += w0 * bfhi(u0.x) + w1 * bfhi(u1.x) + w2 * bfhi(u2.x) + w3 * bfhi(u3.x);
            bx += w0 * bflo(u0.y) + w1 * bflo(u1.y) + w2 * bflo(u2.y) + w3 * bflo(u3.y);
            by += w0 * bfhi(u0.y) + w1 * bfhi(u1.y) + w2 * bfhi(u2.y) + w3 * bfhi(u3.y);
        }
        for (; k < m; k += 4) {
            int kk = k + q;
            bool act = kk < m;
            int s0 = __shfl(adjv, act ? kk : 0, 64);
            float w0 = act ? __expf(lrelu(al1s[s0 * 8 + h] + ald)) : 0.f;
            uint2 u0 = *(const uint2*)(h1b2 + s0 * 32 + r * 2);
            dsum += w0;
            ax += w0 * bflo(u0.x);
            ay += w0 * bfhi(u0.x);
            bx += w0 * bflo(u0.y);
            by += w0 * bfhi(u0.y);
        }
    }
    // reduce across the 4 edge-slot quarters
    dsum += __shfl_xor(dsum, 16, 64); dsum += __shfl_xor(dsum, 32, 64);
    ax   += __shfl_xor(ax,   16, 64); ax   += __shfl_xor(ax,   32, 64);
    ay   += __shfl_xor(ay,   16, 64); ay   += __shfl_xor(ay,   32, 64);
    bx   += __shfl_xor(bx,   16, 64); bx   += __shfl_xor(bx,   32, 64);
    by   += __shfl_xor(by,   16, 64); by   += __shfl_xor(by,   32, 64);

    float inv = 1.f / dsum;
    float v0 = ax * inv + b1[r * 4 + 0];
    float v1 = ay * inv + b1[r * 4 + 1];
    float v2 = bx * inv + b1[r * 4 + 2];
    float v3 = by * inv + b1[r * 4 + 3];
    v0 = v0 > 0.f ? v0 : __expf(v0) - 1.f;   // ELU fused
    v1 = v1 > 0.f ? v1 : __expf(v1) - 1.f;
    v2 = v2 > 0.f ? v2 : __expf(v2) - 1.f;
    v3 = v3 > 0.f ? v3 : __expf(v3) - 1.f;
    if (q == 0) {
        uint2 o;
        o.x = (unsigned)f2bf(v0) | ((unsigned)f2bf(v1) << 16);
        o.y = (unsigned)f2bf(v2) | ((unsigned)f2bf(v3) << 16);
        *(uint2*)(h1e2 + n * 32 + r * 2) = o;
    }
}

// ---------- layer 2 GEMM: LDS-staged h1e rows (coalesced uint2 loads) ----------
__global__ __launch_bounds__(256) void k_gemm2(
    const unsigned* __restrict__ h1e2, const float* __restrict__ W2,
    const float* __restrict__ a2s, const float* __restrict__ a2d,
    unsigned short* __restrict__ h2b, float* __restrict__ al2s, float* __restrict__ al2d)
{
    __shared__ float sW[64 * 16];      // 4 KB
    __shared__ unsigned sh[16][33];    // 16 rows x 32 u32 (+1 pad) = 2112 B
    const int t = threadIdx.x;
    for (int i = t; i < 64 * 16; i += 256) sW[i] = W2[i];
    const int nb = blockIdx.x * 16;    // NN/16 = 6250 exact, no bounds issue
    {
        int idx = t * 2;               // u32 index within the 16x32 block
        int rrow = idx >> 5, rcol = idx & 31;
        uint2 v = *(const uint2*)(h1e2 + (size_t)(nb + rrow) * 32 + rcol);
        sh[rrow][rcol]     = v.x;
        sh[rrow][rcol + 1] = v.y;
    }
    __syncthreads();
    const int ln = t >> 4;             // node slot 0..15
    const int k  = t & 15;
    const int n  = nb + ln;
    float acc = 0.f;
    #pragma unroll
    for (int c2 = 0; c2 < 32; ++c2) {
        unsigned u = sh[ln][c2];       // broadcast across the 16 k-lanes
        acc += bflo(u) * sW[(c2 * 2) * 16 + k] + bfhi(u) * sW[(c2 * 2 + 1) * 16 + k];
    }
    h2b[(size_t)n * 16 + k] = f2bf(acc);
    float vs = acc * a2s[k], vd = acc * a2d[k];
    #pragma unroll
    for (int off = 1; off < 16; off <<= 1) {
        vs += __shfl_xor(vs, off, 64);
        vd += __shfl_xor(vd, off, 64);
    }
    if (k == 0) { al2s[n] = vs; al2d[n] = vd; }
}

// ---------- layer 2 aggregation: 16 edges x 4 lanes, uint2 value loads ----------
__global__ __launch_bounds__(256) void k_agg2(
    const int* __restrict__ row, const int* __restrict__ adj,
    const float* __restrict__ al2s, const float* __restrict__ al2d,
    const unsigned* __restrict__ h2b2, const float* __restrict__ b2,
    float* __restrict__ out)
{
    const int wv = threadIdx.x >> 6, lane = threadIdx.x & 63;
    const int n = blockIdx.x * 4 + wv;
    const float ald = al2d[n];
    const int r0 = row[n], r1 = row[n + 1];

    const int j = lane >> 2;    // edge slot 0..15
    const int r = lane & 3;     // channel quad -> channels 4r..4r+3
    float dsum = 0.f, ax = 0.f, ay = 0.f, bx = 0.f, by = 0.f;
    for (int i = r0; i < r1; i += 16) {
        int i0 = i + j;
        bool act = i0 < r1;
        int s = adj[act ? i0 : r0];
        float w = act ? __expf(lrelu(al2s[s] + ald)) : 0.f;
        uint2 u = *(const uint2*)(h2b2 + s * 8 + r * 2);
        dsum += w;
        ax += w * bflo(u.x);
        ay += w * bfhi(u.x);
        bx += w * bflo(u.y);
        by += w * bfhi(u.y);
    }
    #pragma unroll
    for (int off = 4; off < 64; off <<= 1) {
        dsum += __shfl_xor(dsum, off, 64);
        ax   += __shfl_xor(ax,   off, 64);
        ay   += __shfl_xor(ay,   off, 64);
        bx   += __shfl_xor(bx,   off, 64);
        by   += __shfl_xor(by,   off, 64);
    }
    float inv = 1.f / dsum;
    float v0 = ax * inv + b2[r * 4 + 0];
    float v1 = ay * inv + b2[r * 4 + 1];
    float v2 = bx * inv + b2[r * 4 + 2];
    float v3 = by * inv + b2[r * 4 + 3];

    // log_softmax over 16 channels = 4 lanes x 4
    float mx = fmaxf(fmaxf(v0, v1), fmaxf(v2, v3));
    mx = fmaxf(mx, __shfl_xor(mx, 1, 64));
    mx = fmaxf(mx, __shfl_xor(mx, 2, 64));
    float se = __expf(v0 - mx) + __expf(v1 - mx) + __expf(v2 - mx) + __expf(v3 - mx);
    se += __shfl_xor(se, 1, 64);
    se += __shfl_xor(se, 2, 64);
    float ls = mx + __logf(se);
    if (j == 0)
        *(float4*)(out + (size_t)n * 16 + r * 4) = make_float4(v0 - ls, v1 - ls, v2 - ls, v3 - ls);
}

extern "C" void kernel_launch(void* const* d_in, const int* in_sizes, int n_in,
                              void* d_out, int out_size, void* d_ws, size_t ws_size,
                              hipStream_t stream)
{
    const float* x    = (const float*)d_in[0];
    const int*   eidx = (const int*)d_in[1];
    const float* W1   = (const float*)d_in[2];
    const float* a1s  = (const float*)d_in[3];
    const float* a1d  = (const float*)d_in[4];
    const float* b1   = (const float*)d_in[5];
    const float* W2   = (const float*)d_in[6];
    const float* a2s  = (const float*)d_in[7];
    const float* a2d  = (const float*)d_in[8];
    const float* b2   = (const float*)d_in[9];
    float* out = (float*)d_out;
    float* ws  = (float*)d_ws;

    const int* esrc = eidx;
    const int* edst = eidx + EE;

    int* gcnt = (int*)(ws + OFF_GCNT);
    int* base = (int*)(ws + OFF_BASE);
    int* row  = (int*)(ws + OFF_ROW);
    unsigned* bkt = (unsigned*)(ws + OFF_BKT);
    int* adj  = (int*)(ws + OFF_ADJ);
    unsigned short* h1b = (unsigned short*)(ws + OFF_H1B);
    unsigned short* h1e = (unsigned short*)(ws + OFF_H1E);
    float* al1s  = ws + OFF_AL1S;
    float* al1d  = ws + OFF_AL1D;
    unsigned short* h2b = (unsigned short*)(ws + OFF_H2B);
    float* al2s  = ws + OFF_AL2S;
    float* al2d  = ws + OFF_AL2D;

    hipMemsetAsync(gcnt, 0, 392 * sizeof(int), stream);

    k_binA_gemm1<<<NABLK + NG1, 256, 0, stream>>>(esrc, edst, gcnt, bkt,
                                                  x, W1, a1s, a1d, h1b, al1s, al1d);
    k_scanB<<<1, 512, 0, stream>>>(gcnt, base, row);
    k_binC_gemm1<<<NBKT + NG2, 256, 0, stream>>>(gcnt, base, bkt, row, adj,
                                                 x, W1, a1s, a1d, h1b, al1s, al1d);

    k_agg1 <<<NN / 4, 256, 0, stream>>>(row, adj, al1s, al1d, (const unsigned*)h1b, b1, (unsigned*)h1e);
    k_gemm2<<<NN / 16, 256, 0, stream>>>((const unsigned*)h1e, W2, a2s, a2d, h2b, al2s, al2d);
    k_agg2 <<<NN / 4, 256, 0, stream>>>(row, adj, al2s, al2d, (const unsigned*)h2b, b2, out);
}

// Round 13
// 355.588 us; speedup vs baseline: 1.0165x; 1.0165x over previous
//
#include <hip/hip_runtime.h>
#include <math.h>

#define NN   100000
#define EE   1600000
#define FIN  256
#define NCLS 16
#define NEG  0.2f

#define NEDGE (EE + NN)     // with self-loops
#define WBKT  256           // dsts per bucket
#define NBKT  ((NN + WBKT - 1) / WBKT)   // 391
#define CAP   5120          // per-bucket capacity (mean 4352)
#define ABLK  4096          // edges per binA block
#define NABLK ((NEDGE + ABLK - 1) / ABLK)  // 416
#define NGBLK ((NN + 63) / 64)             // 1563 gemm1 blocks

// ---- workspace layout (4-byte element offsets) ----
#define OFF_GCNT  0                          // [392] zeroed each call
#define OFF_BASE  392                        // [392]
#define OFF_ROW   784                        // [NN+1]
#define OFF_BKT   100788                     // [NBKT*CAP] packed (src<<8)|dlow
#define OFF_ADJ   (OFF_BKT + NBKT*CAP)       // [NEDGE]
#define OFF_H1B   (OFF_ADJ + NEDGE)          // [NN*64] bf16 (pre-attn values)
#define OFF_H1E   (OFF_H1B + NN*32)          // [NN*64] (UNUSED since R13: gemm2 fused into agg1)
#define OFF_AL1S  (OFF_H1E + NN*32)          // [NN*8]
#define OFF_AL1D  (OFF_AL1S + NN*8)          // [NN*8]
#define OFF_H2B   (OFF_AL1D + NN*8)          // [NN*16] bf16
#define OFF_AL2S  (OFF_H2B + NN*8)           // [NN]
#define OFF_AL2D  (OFF_AL2S + NN)            // [NN]

__device__ __forceinline__ float lrelu(float x) { return x >= 0.f ? x : NEG * x; }
__device__ __forceinline__ unsigned short f2bf(float x) {
    unsigned u = __float_as_uint(x);
    return (unsigned short)((u + 0x7FFF + ((u >> 16) & 1)) >> 16);   // RNE
}
__device__ __forceinline__ float bf2f(unsigned short b) {
    return __uint_as_float(((unsigned)b) << 16);
}
__device__ __forceinline__ float bflo(unsigned u) { return __uint_as_float(u << 16); }
__device__ __forceinline__ float bfhi(unsigned u) { return __uint_as_float(u & 0xFFFF0000u); }

// ================= role bodies for the fused front-end =================

// ---- gemm1 body: 64x64 tile, 4x4 register tile, reg-prefetch dbuf ----
// smem usage: sxT 8704 B + sW 8192 B = 16896 B
__device__ __forceinline__ void gemm1_body(
    char* smem, int n0, int t,
    const float* __restrict__ x, const float* __restrict__ W1,
    const float* __restrict__ a1s, const float* __restrict__ a1d,
    unsigned short* __restrict__ h1b, float* __restrict__ al1s, float* __restrict__ al1d)
{
    float (*sxT)[68] = (float(*)[68])smem;
    float (*sW)[64]  = (float(*)[64])(smem + 32 * 68 * 4);
    const int tr = t >> 4, tc = t & 15;

    const int xr0 = t >> 3,         xf0 = t & 7;
    const int xr1 = (t + 256) >> 3, xf1 = (t + 256) & 7;
    const int wr0 = t >> 4,         wf0 = t & 15;
    const int wr1 = (t + 256) >> 4, wf1 = (t + 256) & 15;
    const int nx0 = n0 + xr0, nx1 = n0 + xr1;

    float acc[4][4] = {};
    float4 px0, px1, pw0, pw1;

    px0 = (nx0 < NN) ? *(const float4*)(x + (size_t)nx0 * FIN + xf0 * 4)
                     : make_float4(0.f, 0.f, 0.f, 0.f);
    px1 = (nx1 < NN) ? *(const float4*)(x + (size_t)nx1 * FIN + xf1 * 4)
                     : make_float4(0.f, 0.f, 0.f, 0.f);
    pw0 = *(const float4*)(W1 + (size_t)wr0 * 64 + wf0 * 4);
    pw1 = *(const float4*)(W1 + (size_t)wr1 * 64 + wf1 * 4);

    for (int kc = 0; kc < 256; kc += 32) {
        __syncthreads();
        sxT[xf0 * 4 + 0][xr0] = px0.x;
        sxT[xf0 * 4 + 1][xr0] = px0.y;
        sxT[xf0 * 4 + 2][xr0] = px0.z;
        sxT[xf0 * 4 + 3][xr0] = px0.w;
        sxT[xf1 * 4 + 0][xr1] = px1.x;
        sxT[xf1 * 4 + 1][xr1] = px1.y;
        sxT[xf1 * 4 + 2][xr1] = px1.z;
        sxT[xf1 * 4 + 3][xr1] = px1.w;
        *(float4*)&sW[wr0][wf0 * 4] = pw0;
        *(float4*)&sW[wr1][wf1 * 4] = pw1;
        __syncthreads();

        if (kc + 32 < 256) {
            int kn = kc + 32;
            px0 = (nx0 < NN) ? *(const float4*)(x + (size_t)nx0 * FIN + kn + xf0 * 4)
                             : make_float4(0.f, 0.f, 0.f, 0.f);
            px1 = (nx1 < NN) ? *(const float4*)(x + (size_t)nx1 * FIN + kn + xf1 * 4)
                             : make_float4(0.f, 0.f, 0.f, 0.f);
            pw0 = *(const float4*)(W1 + (size_t)(kn + wr0) * 64 + wf0 * 4);
            pw1 = *(const float4*)(W1 + (size_t)(kn + wr1) * 64 + wf1 * 4);
        }

        #pragma unroll
        for (int k = 0; k < 32; ++k) {
            float4 a = *(const float4*)&sxT[k][tr * 4];
            float4 b = *(const float4*)&sW[k][tc * 4];
            acc[0][0] += a.x * b.x; acc[0][1] += a.x * b.y; acc[0][2] += a.x * b.z; acc[0][3] += a.x * b.w;
            acc[1][0] += a.y * b.x; acc[1][1] += a.y * b.y; acc[1][2] += a.y * b.z; acc[1][3] += a.y * b.w;
            acc[2][0] += a.z * b.x; acc[2][1] += a.z * b.y; acc[2][2] += a.z * b.z; acc[2][3] += a.z * b.w;
            acc[3][0] += a.w * b.x; acc[3][1] += a.w * b.y; acc[3][2] += a.w * b.z; acc[3][3] += a.w * b.w;
        }
    }

    #pragma unroll
    for (int j = 0; j < 4; ++j) {
        int n = n0 + tr * 4 + j;
        if (n < NN) {
            ushort4 v = make_ushort4(f2bf(acc[j][0]), f2bf(acc[j][1]), f2bf(acc[j][2]), f2bf(acc[j][3]));
            *(ushort4*)(h1b + (size_t)n * 64 + tc * 4) = v;
        }
    }

    float sa[4], da[4];
    #pragma unroll
    for (int u = 0; u < 4; ++u) { sa[u] = a1s[tc * 4 + u]; da[u] = a1d[tc * 4 + u]; }
    #pragma unroll
    for (int j = 0; j < 4; ++j) {
        float vs = acc[j][0] * sa[0] + acc[j][1] * sa[1] + acc[j][2] * sa[2] + acc[j][3] * sa[3];
        float vd = acc[j][0] * da[0] + acc[j][1] * da[1] + acc[j][2] * da[2] + acc[j][3] * da[3];
        vs += __shfl_xor(vs, 1, 64);
        vd += __shfl_xor(vd, 1, 64);
        int n = n0 + tr * 4 + j;
        if (!(tc & 1) && n < NN) {
            al1s[n * 8 + (tc >> 1)] = vs;
            al1d[n * 8 + (tc >> 1)] = vd;
        }
    }
}

// ---- binA body: bin edges by dst>>8.  smem: 2*NBKT*4 = 3128 B ----
__device__ __forceinline__ void binA_body(
    char* smem, int blk, int t,
    const int* __restrict__ esrc, const int* __restrict__ edst,
    int* __restrict__ gcnt, unsigned* __restrict__ bkt)
{
    int* lcnt  = (int*)smem;
    int* lbase = lcnt + NBKT;
    const int e0 = blk * ABLK;
    for (int i = t; i < NBKT; i += 256) lcnt[i] = 0;
    __syncthreads();

    unsigned wrd[16];
    unsigned short bb[16], ll[16];
    #pragma unroll
    for (int j = 0; j < 16; ++j) {
        int ei = e0 + j * 256 + t;
        bb[j] = 0xFFFFu;
        if (ei < NEDGE) {
            int s, d;
            if (ei < EE) { s = esrc[ei]; d = edst[ei]; } else { s = d = ei - EE; }
            int b = d >> 8;
            wrd[j] = ((unsigned)s << 8) | (unsigned)(d & 255);
            bb[j] = (unsigned short)b;
            ll[j] = (unsigned short)atomicAdd(&lcnt[b], 1);
        }
    }
    __syncthreads();
    for (int i = t; i < NBKT; i += 256)
        lbase[i] = lcnt[i] ? atomicAdd(&gcnt[i], lcnt[i]) : 0;
    __syncthreads();
    #pragma unroll
    for (int j = 0; j < 16; ++j) {
        if (bb[j] != 0xFFFFu) {
            int b = bb[j];
            bkt[(size_t)b * CAP + lbase[b] + ll[j]] = wrd[j];
        }
    }
}

// fused front-end: binA (blocks 0..NABLK-1)  ||  full gemm1 (rest)
__global__ __launch_bounds__(256) void k_binA_gemm1(
    const int* __restrict__ esrc, const int* __restrict__ edst,
    int* __restrict__ gcnt, unsigned* __restrict__ bkt,
    const float* __restrict__ x, const float* __restrict__ W1,
    const float* __restrict__ a1s, const float* __restrict__ a1d,
    unsigned short* __restrict__ h1b, float* __restrict__ al1s, float* __restrict__ al1d)
{
    __shared__ __align__(16) char smem[16896];   // union of roles (max, not sum)
    const int t = threadIdx.x;
    if (blockIdx.x < NABLK)
        binA_body(smem, blockIdx.x, t, esrc, edst, gcnt, bkt);
    else
        gemm1_body(smem, (blockIdx.x - NABLK) * 64, t, x, W1, a1s, a1d, h1b, al1s, al1d);
}

// ---------- CSR build, phase B: scan bucket counts -> bases ----------
__global__ __launch_bounds__(512) void k_scanB(
    const int* __restrict__ gcnt, int* __restrict__ base, int* __restrict__ row)
{
    __shared__ int s[512];
    int t = threadIdx.x;
    int v = (t < NBKT) ? gcnt[t] : 0;
    s[t] = v;
    __syncthreads();
    for (int off = 1; off < 512; off <<= 1) {
        int u = (t >= off) ? s[t - off] : 0;
        __syncthreads();
        s[t] += u;
        __syncthreads();
    }
    if (t <= NBKT) base[t] = s[t] - v;   // exclusive; base[NBKT] = NEDGE
    if (t == 0) row[NN] = NEDGE;
}

// ---------- CSR build, phase C: per-bucket local sort -> row + adj ----------
__global__ __launch_bounds__(256) void k_binC(
    const int* __restrict__ gcnt, const int* __restrict__ base,
    const unsigned* __restrict__ bkt, int* __restrict__ row, int* __restrict__ adj)
{
    __shared__ unsigned wd[CAP];          // 20 KB stage
    __shared__ int hist[256], pref[256], cnt2[256];
    const int g = blockIdx.x, t = threadIdx.x;
    const int cn = gcnt[g], bs = base[g];
    hist[t] = 0; cnt2[t] = 0;
    __syncthreads();
    for (int i = t; i < cn; i += 256) {
        unsigned w = bkt[(size_t)g * CAP + i];
        wd[i] = w;
        atomicAdd(&hist[w & 255], 1);
    }
    __syncthreads();
    int v = hist[t];
    pref[t] = v;
    __syncthreads();
    for (int off = 1; off < 256; off <<= 1) {
        int u = (t >= off) ? pref[t - off] : 0;
        __syncthreads();
        pref[t] += u;
        __syncthreads();
    }
    int ex = pref[t] - v;                 // exclusive local prefix
    int n = g * 256 + t;
    if (n < NN) row[n] = bs + ex;
    pref[t] = ex;
    __syncthreads();
    for (int i = t; i < cn; i += 256) {
        unsigned w = wd[i];
        int dl = w & 255;
        int p = atomicAdd(&cnt2[dl], 1);
        adj[bs + pref[dl] + p] = (int)(w >> 8);
    }
}

// ---------- layer 1 aggregation + FUSED layer 2 GEMM epilogue ----------
// After the cross-q shfl reductions, every lane holds its node's finished
// (normalized+bias+ELU) channels 4r..4r+3 in registers -> compute the 64x16
// layer-2 GEMM in-wave (lane (q,r): channels 4r..4r+3 into outputs 4q..4q+3,
// W2 staged in LDS [64][17]), reduce over r, write h2b/al2s/al2d directly.
// h1e never materializes (saves its 12.8MB write + 12.8MB read + a launch).
__global__ __launch_bounds__(256) void k_agg1(
    const int* __restrict__ row, const int* __restrict__ adj,
    const float* __restrict__ al1s, const float* __restrict__ al1d,
    const unsigned* __restrict__ h1b2, const float* __restrict__ b1,
    const float* __restrict__ W2, const float* __restrict__ a2s, const float* __restrict__ a2d,
    unsigned short* __restrict__ h2b, float* __restrict__ al2s, float* __restrict__ al2d)
{
    __shared__ float sW2[64 * 17];     // padded: stride 17 breaks bank alignment
    const int t = threadIdx.x;
    for (int i = t; i < 64 * 16; i += 256) sW2[(i >> 4) * 17 + (i & 15)] = W2[i];
    __syncthreads();

    const int wv = t >> 6, lane = t & 63;
    const int n = blockIdx.x * 4 + wv;
    const int q = lane >> 4;           // edge slot in 4-pack
    const int r = lane & 15;           // channel quad -> channels 4r..4r+3
    const int h = r >> 1;              // head
    const float ald = al1d[n * 8 + h];
    const int r0 = row[n], r1 = row[n + 1];

    float dsum = 0.f, ax = 0.f, ay = 0.f, bx = 0.f, by = 0.f;
    for (int c0 = r0; c0 < r1; c0 += 64) {
        int li = c0 + lane;
        int adjv = adj[li < r1 ? li : r0];      // chunk preload, coalesced
        int m = r1 - c0; if (m > 64) m = 64;
        int k = 0;
        for (; k + 16 <= m; k += 16) {
            int s0 = __shfl(adjv, k + 0  + q, 64);
            int s1 = __shfl(adjv, k + 4  + q, 64);
            int s2 = __shfl(adjv, k + 8  + q, 64);
            int s3 = __shfl(adjv, k + 12 + q, 64);
            float a0 = al1s[s0 * 8 + h];
            float a1 = al1s[s1 * 8 + h];
            float a2 = al1s[s2 * 8 + h];
            float a3 = al1s[s3 * 8 + h];
            uint2 u0 = *(const uint2*)(h1b2 + s0 * 32 + r * 2);
            uint2 u1 = *(const uint2*)(h1b2 + s1 * 32 + r * 2);
            uint2 u2 = *(const uint2*)(h1b2 + s2 * 32 + r * 2);
            uint2 u3 = *(const uint2*)(h1b2 + s3 * 32 + r * 2);
            float w0 = __expf(lrelu(a0 + ald));
            float w1 = __expf(lrelu(a1 + ald));
            float w2 = __expf(lrelu(a2 + ald));
            float w3 = __expf(lrelu(a3 + ald));
            dsum += (w0 + w1) + (w2 + w3);
            ax += w0 * bflo(u0.x) + w1 * bflo(u1.x) + w2 * bflo(u2.x) + w3 * bflo(u3.x);
            ay += w0 * bfhi(u0.x) + w1 * bfhi(u1.x) + w2 * bfhi(u2.x) + w3 * bfhi(u3.x);
            bx += w0 * bflo(u0.y) + w1 * bflo(u1.y) + w2 * bflo(u2.y) + w3 * bflo(u3.y);
            by += w0 * bfhi(u0.y) + w1 * bfhi(u1.y) + w2 * bfhi(u2.y) + w3 * bfhi(u3.y);
        }
        for (; k < m; k += 4) {
            int kk = k + q;
            bool act = kk < m;
            int s0 = __shfl(adjv, act ? kk : 0, 64);
            float w0 = act ? __expf(lrelu(al1s[s0 * 8 + h] + ald)) : 0.f;
            uint2 u0 = *(const uint2*)(h1b2 + s0 * 32 + r * 2);
            dsum += w0;
            ax += w0 * bflo(u0.x);
            ay += w0 * bfhi(u0.x);
            bx += w0 * bflo(u0.y);
            by += w0 * bfhi(u0.y);
        }
    }
    // reduce across the 4 edge-slot quarters -> all lanes hold full sums
    dsum += __shfl_xor(dsum, 16, 64); dsum += __shfl_xor(dsum, 32, 64);
    ax   += __shfl_xor(ax,   16, 64); ax   += __shfl_xor(ax,   32, 64);
    ay   += __shfl_xor(ay,   16, 64); ay   += __shfl_xor(ay,   32, 64);
    bx   += __shfl_xor(bx,   16, 64); bx   += __shfl_xor(bx,   32, 64);
    by   += __shfl_xor(by,   16, 64); by   += __shfl_xor(by,   32, 64);

    float inv = 1.f / dsum;
    float v0 = ax * inv + b1[r * 4 + 0];
    float v1 = ay * inv + b1[r * 4 + 1];
    float v2 = bx * inv + b1[r * 4 + 2];
    float v3 = by * inv + b1[r * 4 + 3];
    v0 = v0 > 0.f ? v0 : __expf(v0) - 1.f;   // ELU fused
    v1 = v1 > 0.f ? v1 : __expf(v1) - 1.f;
    v2 = v2 > 0.f ? v2 : __expf(v2) - 1.f;
    v3 = v3 > 0.f ? v3 : __expf(v3) - 1.f;

    // ---- fused layer-2 GEMM epilogue ----
    const int kb = q * 4;              // this lane's output quad k = kb..kb+3
    float p0 = 0.f, p1 = 0.f, p2 = 0.f, p3 = 0.f;
    {
        const float* wrow0 = &sW2[(r * 4 + 0) * 17 + kb];
        const float* wrow1 = &sW2[(r * 4 + 1) * 17 + kb];
        const float* wrow2 = &sW2[(r * 4 + 2) * 17 + kb];
        const float* wrow3 = &sW2[(r * 4 + 3) * 17 + kb];
        p0 = v0 * wrow0[0] + v1 * wrow1[0] + v2 * wrow2[0] + v3 * wrow3[0];
        p1 = v0 * wrow0[1] + v1 * wrow1[1] + v2 * wrow2[1] + v3 * wrow3[1];
        p2 = v0 * wrow0[2] + v1 * wrow1[2] + v2 * wrow2[2] + v3 * wrow3[2];
        p3 = v0 * wrow0[3] + v1 * wrow1[3] + v2 * wrow2[3] + v3 * wrow3[3];
    }
    #pragma unroll
    for (int off = 1; off < 16; off <<= 1) {   // reduce over r (channel quads)
        p0 += __shfl_xor(p0, off, 64);
        p1 += __shfl_xor(p1, off, 64);
        p2 += __shfl_xor(p2, off, 64);
        p3 += __shfl_xor(p3, off, 64);
    }
    if (r == 0) {
        ushort4 o = make_ushort4(f2bf(p0), f2bf(p1), f2bf(p2), f2bf(p3));
        *(ushort4*)(h2b + (size_t)n * 16 + kb) = o;
    }
    float vs = p0 * a2s[kb] + p1 * a2s[kb + 1] + p2 * a2s[kb + 2] + p3 * a2s[kb + 3];
    float vd = p0 * a2d[kb] + p1 * a2d[kb + 1] + p2 * a2d[kb + 2] + p3 * a2d[kb + 3];
    vs += __shfl_xor(vs, 16, 64); vs += __shfl_xor(vs, 32, 64);
    vd += __shfl_xor(vd, 16, 64); vd += __shfl_xor(vd, 32, 64);
    if (lane == 0) { al2s[n] = vs; al2d[n] = vd; }
}

// ---------- layer 2 aggregation: 16 edges x 4 lanes, uint2 value loads ----------
__global__ __launch_bounds__(256) void k_agg2(
    const int* __restrict__ row, const int* __restrict__ adj,
    const float* __restrict__ al2s, const float* __restrict__ al2d,
    const unsigned* __restrict__ h2b2, const float* __restrict__ b2,
    float* __restrict__ out)
{
    const int wv = threadIdx.x >> 6, lane = threadIdx.x & 63;
    const int n = blockIdx.x * 4 + wv;
    const float ald = al2d[n];
    const int r0 = row[n], r1 = row[n + 1];

    const int j = lane >> 2;    // edge slot 0..15
    const int r = lane & 3;     // channel quad -> channels 4r..4r+3
    float dsum = 0.f, ax = 0.f, ay = 0.f, bx = 0.f, by = 0.f;
    for (int i = r0; i < r1; i += 16) {
        int i0 = i + j;
        bool act = i0 < r1;
        int s = adj[act ? i0 : r0];
        float w = act ? __expf(lrelu(al2s[s] + ald)) : 0.f;
        uint2 u = *(const uint2*)(h2b2 + s * 8 + r * 2);
        dsum += w;
        ax += w * bflo(u.x);
        ay += w * bfhi(u.x);
        bx += w * bflo(u.y);
        by += w * bfhi(u.y);
    }
    #pragma unroll
    for (int off = 4; off < 64; off <<= 1) {
        dsum += __shfl_xor(dsum, off, 64);
        ax   += __shfl_xor(ax,   off, 64);
        ay   += __shfl_xor(ay,   off, 64);
        bx   += __shfl_xor(bx,   off, 64);
        by   += __shfl_xor(by,   off, 64);
    }
    float inv = 1.f / dsum;
    float v0 = ax * inv + b2[r * 4 + 0];
    float v1 = ay * inv + b2[r * 4 + 1];
    float v2 = bx * inv + b2[r * 4 + 2];
    float v3 = by * inv + b2[r * 4 + 3];

    // log_softmax over 16 channels = 4 lanes x 4
    float mx = fmaxf(fmaxf(v0, v1), fmaxf(v2, v3));
    mx = fmaxf(mx, __shfl_xor(mx, 1, 64));
    mx = fmaxf(mx, __shfl_xor(mx, 2, 64));
    float se = __expf(v0 - mx) + __expf(v1 - mx) + __expf(v2 - mx) + __expf(v3 - mx);
    se += __shfl_xor(se, 1, 64);
    se += __shfl_xor(se, 2, 64);
    float ls = mx + __logf(se);
    if (j == 0)
        *(float4*)(out + (size_t)n * 16 + r * 4) = make_float4(v0 - ls, v1 - ls, v2 - ls, v3 - ls);
}

extern "C" void kernel_launch(void* const* d_in, const int* in_sizes, int n_in,
                              void* d_out, int out_size, void* d_ws, size_t ws_size,
                              hipStream_t stream)
{
    const float* x    = (const float*)d_in[0];
    const int*   eidx = (const int*)d_in[1];
    const float* W1   = (const float*)d_in[2];
    const float* a1s  = (const float*)d_in[3];
    const float* a1d  = (const float*)d_in[4];
    const float* b1   = (const float*)d_in[5];
    const float* W2   = (const float*)d_in[6];
    const float* a2s  = (const float*)d_in[7];
    const float* a2d  = (const float*)d_in[8];
    const float* b2   = (const float*)d_in[9];
    float* out = (float*)d_out;
    float* ws  = (float*)d_ws;

    const int* esrc = eidx;
    const int* edst = eidx + EE;

    int* gcnt = (int*)(ws + OFF_GCNT);
    int* base = (int*)(ws + OFF_BASE);
    int* row  = (int*)(ws + OFF_ROW);
    unsigned* bkt = (unsigned*)(ws + OFF_BKT);
    int* adj  = (int*)(ws + OFF_ADJ);
    unsigned short* h1b = (unsigned short*)(ws + OFF_H1B);
    float* al1s  = ws + OFF_AL1S;
    float* al1d  = ws + OFF_AL1D;
    unsigned short* h2b = (unsigned short*)(ws + OFF_H2B);
    float* al2s  = ws + OFF_AL2S;
    float* al2d  = ws + OFF_AL2D;

    hipMemsetAsync(gcnt, 0, 392 * sizeof(int), stream);

    k_binA_gemm1<<<NABLK + NGBLK, 256, 0, stream>>>(esrc, edst, gcnt, bkt,
                                                    x, W1, a1s, a1d, h1b, al1s, al1d);
    k_scanB<<<1,    512, 0, stream>>>(gcnt, base, row);
    k_binC <<<NBKT, 256, 0, stream>>>(gcnt, base, bkt, row, adj);

    k_agg1 <<<NN / 4, 256, 0, stream>>>(row, adj, al1s, al1d, (const unsigned*)h1b, b1,
                                        W2, a2s, a2d, h2b, al2s, al2d);
    k_agg2 <<<NN / 4, 256, 0, stream>>>(row, adj, al2s, al2d, (const unsigned*)h2b, b2, out);
}